// Round 4
// baseline (455.853 us; speedup 1.0000x reference)
//
#include <hip/hip_runtime.h>

typedef unsigned int uint_t;
typedef unsigned short ushort_t;

using f32x4 = __attribute__((ext_vector_type(4))) float;
using bf16x8 = __attribute__((ext_vector_type(8))) short;

#define D_MODEL 2048
#define N_HEADS 16
#define N_KV    4
#define HD      128
#define KV_DIM  (N_KV * HD)          // 512
#define NQKV    (D_MODEL + 2*KV_DIM) // 3072
#define SEQ     2048
#define NB      4
#define MROWS   (NB * SEQ)           // 8192
#define NKT     32                   // K/64, K=2048 for both GEMMs
#define SM_SCALE 0.08838834764831845f  // 1/sqrt(128)

__device__ __forceinline__ ushort_t f2bf(float f) {
    uint_t u = __float_as_uint(f);
    u = (u + 0x7FFFu + ((u >> 16) & 1u)) >> 16;   // RNE
    return (ushort_t)u;
}

// async global->LDS, 16 B/lane, lands at (wave-uniform lds base) + lane*16
__device__ __forceinline__ void gload16(const ushort_t* g, ushort_t* l) {
    __builtin_amdgcn_global_load_lds(
        (const __attribute__((address_space(1))) unsigned int*)g,
        (__attribute__((address_space(3))) unsigned int*)l, 16, 0, 0);
}

#define VMCNT(N) asm volatile("s_waitcnt vmcnt(" #N ")")

// ---------------------------------------------------------------- conv_x
__global__ __launch_bounds__(256) void conv_x_kernel(const float* __restrict__ in,
                                                     ushort_t* __restrict__ out, int n) {
    int i = (blockIdx.x * 256 + threadIdx.x) * 4;
    if (i >= n) return;
    float4 v = *(const float4*)&in[i];
    ushort_t o[4] = {f2bf(v.x), f2bf(v.y), f2bf(v.z), f2bf(v.w)};
    *(uint2*)&out[i] = *(uint2*)o;
}

// ------------------------------------------------------ transpose + cast
// W [K][Nout] fp32 -> WT [Nout][K] bf16
__global__ __launch_bounds__(256) void conv_wt_kernel(const float* __restrict__ W,
                                                      ushort_t* __restrict__ WT,
                                                      int K, int Nout) {
    __shared__ float tile[32][33];
    int n0 = blockIdx.x * 32, k0 = blockIdx.y * 32;
    int tx = threadIdx.x, ty = threadIdx.y;  // (32, 8)
    for (int i = 0; i < 4; ++i)
        tile[ty + 8*i][tx] = W[(size_t)(k0 + ty + 8*i) * Nout + n0 + tx];
    __syncthreads();
    for (int i = 0; i < 4; ++i)
        WT[(size_t)(n0 + ty + 8*i) * K + k0 + tx] = f2bf(tile[tx][ty + 8*i]);
}

// ======================================================================
// 128x128 GEMM core (R0-verified, 129 us on qkv): 4 waves, dbuf LDS,
// one __syncthreads per 64-K step. ~800 TF per-active; qkv grid 64x24 =
// 1536 blocks = 6/CU perfectly balanced (the 256x256 core is faster
// per-block but 384 blocks = 1.5/CU tail cost it 25% -> net worse).
// ======================================================================
#define GEMM_STAGE(A, BT, k0, b)                                                   \
    for (int i = 0; i < 4; ++i) {                                                  \
        int ci = (w * 4 + i) * 64 + lane;                                          \
        int row = ci >> 3, c = ci & 7, cg = c ^ (row & 7);                         \
        gload16(&A [(size_t)(bm + row) * K + (k0) + cg * 8], &As[b][0][0] + (w * 4 + i) * 512); \
        gload16(&BT[(size_t)(bn + row) * K + (k0) + cg * 8], &Bs[b][0][0] + (w * 4 + i) * 512); \
    }

#define GEMM_MAIN_LOOP(A, BT, K)                                                   \
    GEMM_STAGE(A, BT, 0, 0)                                                        \
    {                                                                              \
        int buf = 0;                                                               \
        for (int k0 = 0; k0 < K; k0 += 64) {                                       \
            __syncthreads();            /* drains prefetch into As[buf] */         \
            if (k0 + 64 < K) { GEMM_STAGE(A, BT, k0 + 64, buf ^ 1) }               \
            for (int kk = 0; kk < 64; kk += 32) {                                  \
                bf16x8 af[4], bfr[4];                                              \
                int k4 = kk >> 3;                                                  \
                for (int i = 0; i < 4; ++i)                                        \
                    af[i]  = *(const bf16x8*)&As[buf][mb + i * 16 + r][((k4 + quad) ^ (r & 7)) * 8]; \
                for (int j = 0; j < 4; ++j)                                        \
                    bfr[j] = *(const bf16x8*)&Bs[buf][nb + j * 16 + r][((k4 + quad) ^ (r & 7)) * 8]; \
                for (int i = 0; i < 4; ++i)                                        \
                    for (int j = 0; j < 4; ++j)                                    \
                        acc[i][j] = __builtin_amdgcn_mfma_f32_16x16x32_bf16(af[i], bfr[j], acc[i][j], 0, 0, 0); \
            }                                                                      \
            buf ^= 1;                                                              \
        }                                                                          \
    }

// ------------------------------------- QKV GEMM + fused RMSNorm/rearrange
// (R0-verified 128^2 version.) N-tile 128 == one head group. g = blockIdx.y:
// 0..15 -> Q (rmsnorm*q_scale*SM), 16..19 -> K (rmsnorm*k_scale),
// 20..23 -> V transposed directly to Vt [nk][d][l].
__global__ __launch_bounds__(256) void gemm_qkv_kernel(const ushort_t* __restrict__ A,
                                                       const ushort_t* __restrict__ BT,
                                                       const float* __restrict__ bias,
                                                       const float* __restrict__ q_scale,
                                                       const float* __restrict__ k_scale,
                                                       ushort_t* __restrict__ Q,
                                                       ushort_t* __restrict__ Kb,
                                                       ushort_t* __restrict__ Vt) {
    __shared__ ushort_t As[2][128][64];
    __shared__ ushort_t Bs[2][128][64];
    const int K = D_MODEL;
    const int bm = blockIdx.x * 128, bn = blockIdx.y * 128;
    const int t = threadIdx.x;
    const int w = t >> 6, lane = t & 63, quad = lane >> 4, r = lane & 15;
    const int mb = (w >> 1) * 64, nb = (w & 1) * 64;
    f32x4 acc[4][4] = {};
    GEMM_MAIN_LOOP(A, BT, K)

    const int g = blockIdx.y;
    float bj[4];
    for (int j = 0; j < 4; ++j) bj[j] = bias[bn + nb + j * 16 + r];
    for (int i = 0; i < 4; ++i)
        for (int j = 0; j < 4; ++j)
            for (int reg = 0; reg < 4; ++reg) acc[i][j][reg] += bj[j];

    const int n = bm >> 11, lb = bm & 2047;
    if (g < 20) {
        __syncthreads();                              // LDS free; reuse for ssum
        float* ssum = (float*)&As[0][0][0];           // [2][128]
        for (int i = 0; i < 4; ++i)
            for (int reg = 0; reg < 4; ++reg) {
                float p = 0.f;
                for (int j = 0; j < 4; ++j) p += acc[i][j][reg] * acc[i][j][reg];
                p += __shfl_xor(p, 1); p += __shfl_xor(p, 2);
                p += __shfl_xor(p, 4); p += __shfl_xor(p, 8);
                if (r == 0) ssum[(w & 1) * 128 + mb + i * 16 + quad * 4 + reg] = p;
            }
        __syncthreads();
        const float* scp = (g < 16) ? q_scale : k_scale;
        const float smul = (g < 16) ? SM_SCALE : 1.0f;
        float scj[4];
        for (int j = 0; j < 4; ++j) scj[j] = scp[nb + j * 16 + r];
        ushort_t* dst = (g < 16) ? (Q  + (size_t)(n * 16 + g) * SEQ * HD)
                                 : (Kb + (size_t)(n * 4 + g - 16) * SEQ * HD);
        for (int i = 0; i < 4; ++i)
            for (int reg = 0; reg < 4; ++reg) {
                int rl = mb + i * 16 + quad * 4 + reg;
                float ss = ssum[rl] + ssum[128 + rl];
                float iv = rsqrtf(ss * (1.0f / 128.0f) + 1e-6f) * smul;
                size_t lrow = lb + rl;
                for (int j = 0; j < 4; ++j) {
                    int d = nb + j * 16 + r;
                    dst[lrow * HD + d] = f2bf(acc[i][j][reg] * iv * scj[j]);
                }
            }
    } else {
        // V: write transposed directly, packing 4 consecutive l per lane (8 B)
        ushort_t* dstT = Vt + (size_t)(n * 4 + g - 20) * HD * SEQ;
        for (int i = 0; i < 4; ++i)
            for (int j = 0; j < 4; ++j) {
                int d = nb + j * 16 + r;
                ushort_t o[4];
                for (int reg = 0; reg < 4; ++reg) o[reg] = f2bf(acc[i][j][reg]);
                *(uint2*)&dstT[(size_t)d * SEQ + lb + mb + i * 16 + quad * 4] = *(uint2*)o;
            }
    }
}

// ======================================================================
// 256x256 8-phase GEMM core — kept ONLY for gemm_bt (grid 256 = 1/CU, no
// tail; measured ~11 us faster than the 128^2 version by R0->R3 subtraction).
// ======================================================================
#define G256_PRELUDE                                                               \
    const int t = threadIdx.x;                                                     \
    const int wid = t >> 6, lane = t & 63, quad = lane >> 4, r = lane & 15;        \
    const int wr = wid >> 2, wc = wid & 3;                                         \
    int srow[2], skc[2], sdst[2];                                                  \
    for (int l = 0; l < 2; ++l) {                                                  \
        int u = l * 512 + t, lrow = u >> 3, cc = (u & 7) ^ (lrow & 7);             \
        srow[l] = lrow * 2 + (cc >> 2); skc[l] = (cc & 3) * 8; sdst[l] = u * 8;    \
    }                                                                              \
    const int swz  = ((((r & 1) << 2) | quad) ^ ((r >> 1) & 7)) * 8;               \
    const int aoff = (wr * 64 + (r >> 1)) * 64 + swz;                              \
    const int boff = (wc * 32 + (r >> 1)) * 64 + swz;                              \
    f32x4 acc[8][4] = {};                                                          \
    bf16x8 bfr[4];

#define STAGE1(PTR, ROWBASE, kt, kh, DST, dbuf)                                    \
    if ((kt) < NKT) {                                                              \
        for (int l = 0; l < 2; ++l)                                                \
            gload16(&PTR[(size_t)((ROWBASE) + srow[l]) * 2048 +                    \
                         (kt) * 64 + (kh) * 32 + skc[l]],                          \
                    &DST[dbuf][kh][0] + sdst[l]);                                  \
    }

#define PHASE(buf, kh, mh, STAGE_STMT, VM_STMT)                                    \
    {                                                                              \
        bf16x8 af[4];                                                              \
        for (int i = 0; i < 4; ++i)                                                \
            af[i] = *(const bf16x8*)&As[buf][kh][aoff + ((mh) * 4 + i) * 512];     \
        if ((mh) == 0)                                                             \
            for (int jf = 0; jf < 4; ++jf)                                         \
                bfr[jf] = *(const bf16x8*)&Bs[buf][kh][boff + jf * 512];           \
        STAGE_STMT;                                                                \
        __builtin_amdgcn_s_barrier();                                              \
        __builtin_amdgcn_s_setprio(1);                                             \
        for (int i = 0; i < 4; ++i)                                                \
            for (int jf = 0; jf < 4; ++jf)                                         \
                acc[(mh) * 4 + i][jf] = __builtin_amdgcn_mfma_f32_16x16x32_bf16(   \
                    af[i], bfr[jf], acc[(mh) * 4 + i][jf], 0, 0, 0);               \
        __builtin_amdgcn_s_setprio(0);                                             \
        VM_STMT;                                                                   \
        __builtin_amdgcn_s_barrier();                                              \
    }

#define KTILE(j, buf)                                                              \
    PHASE(buf, 0, 0, STAGE1(Aptr, bm, (j) + 1, 1, As, (buf) ^ 1), ;)               \
    PHASE(buf, 0, 1, STAGE1(Bptr, bn, (j) + 1, 1, Bs, (buf) ^ 1),                  \
          { if ((j) + 1 < NKT) { VMCNT(8); } else { VMCNT(0); } })                 \
    PHASE(buf, 1, 0, STAGE1(Aptr, bm, (j) + 2, 0, As, buf), ;)                     \
    PHASE(buf, 1, 1, STAGE1(Bptr, bn, (j) + 2, 0, Bs, buf),                        \
          { if ((j) + 2 < NKT) { VMCNT(8); }                                       \
            else if ((j) + 1 < NKT) { VMCNT(4); }                                  \
            else { VMCNT(0); } })

#define G256_MAIN_LOOP                                                             \
    STAGE1(Aptr, bm, 0, 0, As, 0);                                                 \
    STAGE1(Bptr, bn, 0, 0, Bs, 0);                                                 \
    STAGE1(Aptr, bm, 0, 1, As, 0);                                                 \
    STAGE1(Bptr, bn, 0, 1, Bs, 0);                                                 \
    STAGE1(Aptr, bm, 1, 0, As, 1);                                                 \
    STAGE1(Bptr, bn, 1, 0, Bs, 1);                                                 \
    VMCNT(8);                                                                      \
    __builtin_amdgcn_s_barrier();                                                  \
    _Pragma("unroll 1")                                                            \
    for (int j = 0; j < NKT; j += 2) {                                             \
        KTILE(j, 0)                                                                \
        KTILE(j + 1, 1)                                                            \
    }

// ---------------------------------------------------- out-projection GEMM
// XCD-aware bijective swizzle (grid 256 = 8 XCDs x 32): XCD x gets all 32
// M-tiles of N-panel x -> its 1 MB B-panel stays L2-resident.
__global__ __launch_bounds__(512, 2) void gemm_bt_kernel(const ushort_t* __restrict__ Aptr,
                                                         const ushort_t* __restrict__ Bptr,
                                                         const float* __restrict__ bias,
                                                         float* __restrict__ C,
                                                         int M, int N, int K) {
    __shared__ __align__(16) ushort_t As[2][2][128 * 64];
    __shared__ __align__(16) ushort_t Bs[2][2][128 * 64];
    const int lin = blockIdx.y * 32 + blockIdx.x;      // 0..255, dispatch order
    const int nl  = (lin & 7) * 32 + (lin >> 3);       // bijective: 256 % 8 == 0
    const int bm = (nl & 31) * 256, bn = (nl >> 5) * 256;
    G256_PRELUDE
    G256_MAIN_LOOP
    for (int i = 0; i < 8; ++i)
        for (int jf = 0; jf < 4; ++jf) {
            int col = bn + wc * 64 + jf * 16 + r;
            float bv = bias[col];
            for (int reg = 0; reg < 4; ++reg) {
                int row = bm + wr * 128 + i * 16 + quad * 4 + reg;
                C[(size_t)row * N + col] = acc[i][jf][reg] + bv;
            }
        }
}

// --------------------------------------------------- flash causal attention
// Structure unchanged from R0; this round adds T5 setprio(1/0) around the
// QK and PV MFMA clusters (m191: attn +4-7%; causal-skip gives the CU
// scheduler wave-role diversity to arbitrate).
__global__ __launch_bounds__(256, 2) void attn_kernel(const ushort_t* __restrict__ Q,
                                                      const ushort_t* __restrict__ K,
                                                      const ushort_t* __restrict__ Vt,
                                                      ushort_t* __restrict__ Y) {
    const int pid = blockIdx.x, h = blockIdx.y, n = blockIdx.z;
    const int kvh = h >> 2;
    const ushort_t* Qp = Q  + (size_t)(n * N_HEADS + h) * SEQ * HD;
    const ushort_t* Kp = K  + (size_t)(n * N_KV + kvh) * SEQ * HD;
    const ushort_t* Vp = Vt + (size_t)(n * N_KV + kvh) * HD * SEQ;   // [d][l]

    __shared__ ushort_t Ks[2][64][128];   // 32 KB, chunk-swizzled, dbuf
    __shared__ ushort_t Vts[2][128][64];  // 32 KB, chunk-swizzled ([d][key]), dbuf
    __shared__ ushort_t Ps[128][64];      // 16 KB, row-chunk-xor swizzled

    const int t = threadIdx.x, w = t >> 6, lane = t & 63, quad = lane >> 4, r = lane & 15;

#define ATTN_STAGE(ct, b)                                                           \
    for (int i = 0; i < 4; ++i) {                                                   \
        int ci = (w * 4 + i) * 64 + lane;                                           \
        {   /* K tile 64x128: 16 chunks/row */                                      \
            int row = ci >> 4, c = ci & 15, cg = c ^ (row & 7);                     \
            gload16(&Kp[(size_t)((ct) * 64 + row) * HD + cg * 8],                   \
                    &Ks[b][0][0] + (w * 4 + i) * 512);                              \
        }                                                                           \
        {   /* Vt tile 128x64: 8 chunks/row */                                      \
            int row = ci >> 3, c = ci & 7, cg = c ^ (row & 7);                      \
            gload16(&Vp[(size_t)row * SEQ + (ct) * 64 + cg * 8],                    \
                    &Vts[b][0][0] + (w * 4 + i) * 512);                             \
        }                                                                           \
    }

    for (int rep = 0; rep < 2; ++rep) {
        const int qt = rep ? (15 - pid) : pid;
        const int q0 = qt * 128;

        __syncthreads();   // prev rep's LDS reads done before restaging buf 0
        ATTN_STAGE(0, 0)

        // Q fragments straight from global (A-layout is contiguous 16B/lane)
        bf16x8 aq[2][4];
        for (int s = 0; s < 2; ++s)
            for (int kc = 0; kc < 4; ++kc)
                aq[s][kc] = *(const bf16x8*)&Qp[(size_t)(q0 + w * 32 + s * 16 + r) * HD + kc * 32 + quad * 8];

        f32x4 oacc[2][8] = {};
        float lsum[2][4] = {};
        const int nct = 2 * qt + 2;
        int buf = 0;

        for (int ct = 0; ct < nct; ++ct) {
            __syncthreads();   // drains DMA into buf; all reads of buf^1 done
            if (ct + 1 < nct) { ATTN_STAGE(ct + 1, buf ^ 1) }

            // skip tiles entirely above the causal boundary for this wave
            if (ct * 64 <= q0 + w * 32 + 31) {
                // S strips [2 x 16 x 64]: QK^T (scale folded into Q)
                f32x4 sacc[2][4] = {};
                __builtin_amdgcn_s_setprio(1);
                for (int kc = 0; kc < 4; ++kc)
                    for (int jt = 0; jt < 4; ++jt) {
                        bf16x8 bk = *(const bf16x8*)&Ks[buf][jt * 16 + r][((kc * 4 + quad) ^ (r & 7)) * 8];
                        sacc[0][jt] = __builtin_amdgcn_mfma_f32_16x16x32_bf16(aq[0][kc], bk, sacc[0][jt], 0, 0, 0);
                        sacc[1][jt] = __builtin_amdgcn_mfma_f32_16x16x32_bf16(aq[1][kc], bk, sacc[1][jt], 0, 0, 0);
                    }
                __builtin_amdgcn_s_setprio(0);

                // fixed-max softmax; P truncated bf16; row-chunk-xor swizzle
                const bool diag = (ct >= 2 * qt);
                for (int s = 0; s < 2; ++s)
                    for (int reg = 0; reg < 4; ++reg) {
                        int prow = w * 32 + s * 16 + quad * 4 + reg;
                        int qg = q0 + prow;
                        float rs = 0.f;
                        for (int jt = 0; jt < 4; ++jt) {
                            float sv = sacc[s][jt][reg];
                            if (diag && (ct * 64 + jt * 16 + r) > qg) sv = -1e30f;
                            float p = __expf(sv);
                            rs += p;
                            int colp = ((((jt * 2 + (r >> 3)) ^ prow) & 7) << 3) | (r & 7);
                            Ps[prow][colp] = (ushort_t)(__float_as_uint(p) >> 16);
                        }
                        lsum[s][reg] += rs;
                    }

                // PV: O[2x16x128] += P @ V ; bv shared by strips; Ps wave-private
                __builtin_amdgcn_s_setprio(1);
                for (int kk = 0; kk < 64; kk += 32) {
                    bf16x8 pa[2];
                    for (int s = 0; s < 2; ++s) {
                        int row = w * 32 + s * 16 + r;
                        pa[s] = *(const bf16x8*)&Ps[row][((((kk >> 3) + quad) ^ row) & 7) * 8];
                    }
                    for (int dt = 0; dt < 8; ++dt) {
                        bf16x8 bv = *(const bf16x8*)&Vts[buf][dt * 16 + r][((((kk >> 3) + quad) ^ (r & 7)) & 7) * 8];
                        oacc[0][dt] = __builtin_amdgcn_mfma_f32_16x16x32_bf16(pa[0], bv, oacc[0][dt], 0, 0, 0);
                        oacc[1][dt] = __builtin_amdgcn_mfma_f32_16x16x32_bf16(pa[1], bv, oacc[1][dt], 0, 0, 0);
                    }
                }
                __builtin_amdgcn_s_setprio(0);
            }
            buf ^= 1;
        }

        // epilogue: end-of-loop row-sum reduction, then Y
        for (int s = 0; s < 2; ++s)
            for (int reg = 0; reg < 4; ++reg) {
                float sv = lsum[s][reg];
                for (int m = 1; m < 16; m <<= 1) sv += __shfl_xor(sv, m);
                float invl = 1.0f / sv;
                int lrow = q0 + w * 32 + s * 16 + quad * 4 + reg;
                size_t base = ((size_t)(n * SEQ + lrow)) * D_MODEL + h * HD;
                for (int dt = 0; dt < 8; ++dt)
                    Y[base + dt * 16 + r] = f2bf(oacc[s][dt][reg] * invl);
            }
    }
#undef ATTN_STAGE
}

// ------------------------------------------------------------------ launch
extern "C" void kernel_launch(void* const* d_in, const int* in_sizes, int n_in,
                              void* d_out, int out_size, void* d_ws, size_t ws_size,
                              hipStream_t stream) {
    const float* x       = (const float*)d_in[0];
    const float* Wqkv    = (const float*)d_in[1];
    const float* bqkv    = (const float*)d_in[2];
    const float* q_scale = (const float*)d_in[3];
    const float* k_scale = (const float*)d_in[4];
    const float* Wout    = (const float*)d_in[5];
    const float* bout    = (const float*)d_in[6];
    float* out = (float*)d_out;

    ushort_t* xb  = (ushort_t*)d_ws;                        // 8192*2048 (later: y)
    ushort_t* WT  = xb  + (size_t)MROWS * D_MODEL;          // 3072*2048 (later: WoutT)
    ushort_t* Qb  = WT  + (size_t)NQKV * D_MODEL;           // 4*16*2048*128
    ushort_t* Kb  = Qb  + (size_t)NB * N_HEADS * SEQ * HD;  // 4*4*2048*128
    ushort_t* Vtb = Kb  + (size_t)NB * N_KV * SEQ * HD;     // 4*4*128*2048

    conv_x_kernel<<<MROWS * D_MODEL / 1024, 256, 0, stream>>>(x, xb, MROWS * D_MODEL);
    conv_wt_kernel<<<dim3(NQKV / 32, D_MODEL / 32), dim3(32, 8), 0, stream>>>(Wqkv, WT, D_MODEL, NQKV);
    gemm_qkv_kernel<<<dim3(MROWS / 128, NQKV / 128), 256, 0, stream>>>(xb, WT, bqkv, q_scale, k_scale, Qb, Kb, Vtb);
    conv_wt_kernel<<<dim3(D_MODEL / 32, D_MODEL / 32), dim3(32, 8), 0, stream>>>(Wout, WT, D_MODEL, D_MODEL);
    attn_kernel<<<dim3(8, N_HEADS, NB), 256, 0, stream>>>(Qb, Kb, Vtb, xb);
    gemm_bt_kernel<<<dim3(MROWS / 256, D_MODEL / 256), 512, 0, stream>>>(xb, WT, bout, out, MROWS, D_MODEL, D_MODEL);
}

// Round 5
// 451.354 us; speedup vs baseline: 1.0100x; 1.0100x over previous
//
#include <hip/hip_runtime.h>

typedef unsigned int uint_t;
typedef unsigned short ushort_t;

using f32x4 = __attribute__((ext_vector_type(4))) float;
using bf16x8 = __attribute__((ext_vector_type(8))) short;

#define D_MODEL 2048
#define N_HEADS 16
#define N_KV    4
#define HD      128
#define KV_DIM  (N_KV * HD)          // 512
#define NQKV    (D_MODEL + 2*KV_DIM) // 3072
#define SEQ     2048
#define NB      4
#define MROWS   (NB * SEQ)           // 8192
#define SM_SCALE 0.08838834764831845f  // 1/sqrt(128)

__device__ __forceinline__ ushort_t f2bf(float f) {
    uint_t u = __float_as_uint(f);
    u = (u + 0x7FFFu + ((u >> 16) & 1u)) >> 16;   // RNE
    return (ushort_t)u;
}

// async global->LDS, 16 B/lane, lands at (wave-uniform lds base) + lane*16
__device__ __forceinline__ void gload16(const ushort_t* g, ushort_t* l) {
    __builtin_amdgcn_global_load_lds(
        (const __attribute__((address_space(1))) unsigned int*)g,
        (__attribute__((address_space(3))) unsigned int*)l, 16, 0, 0);
}

// ---------------------------------------------------------------- conv_x
// 8 floats/thread: 32B read + 16B write per lane (widened from 4/thread)
__global__ __launch_bounds__(256) void conv_x_kernel(const float* __restrict__ in,
                                                     ushort_t* __restrict__ out, int n) {
    int i = (blockIdx.x * 256 + threadIdx.x) * 8;
    if (i >= n) return;
    float4 v0 = *(const float4*)&in[i];
    float4 v1 = *(const float4*)&in[i + 4];
    ushort_t o[8] = {f2bf(v0.x), f2bf(v0.y), f2bf(v0.z), f2bf(v0.w),
                     f2bf(v1.x), f2bf(v1.y), f2bf(v1.z), f2bf(v1.w)};
    *(uint4*)&out[i] = *(uint4*)o;
}

// ------------------------------------------------------ transpose + cast
// W [K][Nout] fp32 -> WT [Nout][K] bf16
__global__ __launch_bounds__(256) void conv_wt_kernel(const float* __restrict__ W,
                                                      ushort_t* __restrict__ WT,
                                                      int K, int Nout) {
    __shared__ float tile[32][33];
    int n0 = blockIdx.x * 32, k0 = blockIdx.y * 32;
    int tx = threadIdx.x, ty = threadIdx.y;  // (32, 8)
    for (int i = 0; i < 4; ++i)
        tile[ty + 8*i][tx] = W[(size_t)(k0 + ty + 8*i) * Nout + n0 + tx];
    __syncthreads();
    for (int i = 0; i < 4; ++i)
        WT[(size_t)(n0 + ty + 8*i) * K + k0 + tx] = f2bf(tile[tx][ty + 8*i]);
}

// ======================================================================
// 128x128 GEMM core (R0-verified: qkv 127-129 us / ~800 TF, MfmaUtil 34%).
// 4 waves, dbuf LDS, one __syncthreads per 64-K step. Used by BOTH GEMMs:
// the 256^2 8-phase port never beat it (R1/R3 A/B: 725 TF/block + tail).
// ======================================================================
#define GEMM_STAGE(A, BT, k0, b)                                                   \
    for (int i = 0; i < 4; ++i) {                                                  \
        int ci = (w * 4 + i) * 64 + lane;                                          \
        int row = ci >> 3, c = ci & 7, cg = c ^ (row & 7);                         \
        gload16(&A [(size_t)(bm + row) * K + (k0) + cg * 8], &As[b][0][0] + (w * 4 + i) * 512); \
        gload16(&BT[(size_t)(bn + row) * K + (k0) + cg * 8], &Bs[b][0][0] + (w * 4 + i) * 512); \
    }

#define GEMM_MAIN_LOOP(A, BT, K)                                                   \
    GEMM_STAGE(A, BT, 0, 0)                                                        \
    {                                                                              \
        int buf = 0;                                                               \
        for (int k0 = 0; k0 < K; k0 += 64) {                                       \
            __syncthreads();            /* drains prefetch into As[buf] */         \
            if (k0 + 64 < K) { GEMM_STAGE(A, BT, k0 + 64, buf ^ 1) }               \
            for (int kk = 0; kk < 64; kk += 32) {                                  \
                bf16x8 af[4], bfr[4];                                              \
                int k4 = kk >> 3;                                                  \
                for (int i = 0; i < 4; ++i)                                        \
                    af[i]  = *(const bf16x8*)&As[buf][mb + i * 16 + r][((k4 + quad) ^ (r & 7)) * 8]; \
                for (int j = 0; j < 4; ++j)                                        \
                    bfr[j] = *(const bf16x8*)&Bs[buf][nb + j * 16 + r][((k4 + quad) ^ (r & 7)) * 8]; \
                for (int i = 0; i < 4; ++i)                                        \
                    for (int j = 0; j < 4; ++j)                                    \
                        acc[i][j] = __builtin_amdgcn_mfma_f32_16x16x32_bf16(af[i], bfr[j], acc[i][j], 0, 0, 0); \
            }                                                                      \
            buf ^= 1;                                                              \
        }                                                                          \
    }

// ---------------------------------------------------- out-projection GEMM
__global__ __launch_bounds__(256) void gemm_bt_kernel(const ushort_t* __restrict__ A,
                                                      const ushort_t* __restrict__ BT,
                                                      const float* __restrict__ bias,
                                                      float* __restrict__ C,
                                                      int M, int N, int K) {
    __shared__ ushort_t As[2][128][64];
    __shared__ ushort_t Bs[2][128][64];
    const int bm = blockIdx.x * 128, bn = blockIdx.y * 128;
    const int t = threadIdx.x;
    const int w = t >> 6, lane = t & 63, quad = lane >> 4, r = lane & 15;
    const int mb = (w >> 1) * 64, nb = (w & 1) * 64;
    f32x4 acc[4][4] = {};
    GEMM_MAIN_LOOP(A, BT, K)
    for (int i = 0; i < 4; ++i)
        for (int j = 0; j < 4; ++j)
            for (int reg = 0; reg < 4; ++reg) {
                int row = bm + mb + i * 16 + quad * 4 + reg;
                int col = bn + nb + j * 16 + r;
                C[(size_t)row * N + col] = acc[i][j][reg] + bias[col];
            }
}

// ------------------------------------- QKV GEMM + fused RMSNorm/rearrange
// N-tile 128 == one head group. g = blockIdx.y: 0..15 -> Q (rmsnorm*q_scale*SM),
// 16..19 -> K (rmsnorm*k_scale), 20..23 -> V transposed directly to Vt [nk][d][l].
__global__ __launch_bounds__(256) void gemm_qkv_kernel(const ushort_t* __restrict__ A,
                                                       const ushort_t* __restrict__ BT,
                                                       const float* __restrict__ bias,
                                                       const float* __restrict__ q_scale,
                                                       const float* __restrict__ k_scale,
                                                       ushort_t* __restrict__ Q,
                                                       ushort_t* __restrict__ Kb,
                                                       ushort_t* __restrict__ Vt) {
    __shared__ ushort_t As[2][128][64];
    __shared__ ushort_t Bs[2][128][64];
    const int K = D_MODEL;
    const int bm = blockIdx.x * 128, bn = blockIdx.y * 128;
    const int t = threadIdx.x;
    const int w = t >> 6, lane = t & 63, quad = lane >> 4, r = lane & 15;
    const int mb = (w >> 1) * 64, nb = (w & 1) * 64;
    f32x4 acc[4][4] = {};
    GEMM_MAIN_LOOP(A, BT, K)

    const int g = blockIdx.y;
    float bj[4];
    for (int j = 0; j < 4; ++j) bj[j] = bias[bn + nb + j * 16 + r];
    for (int i = 0; i < 4; ++i)
        for (int j = 0; j < 4; ++j)
            for (int reg = 0; reg < 4; ++reg) acc[i][j][reg] += bj[j];

    const int n = bm >> 11, lb = bm & 2047;
    if (g < 20) {
        __syncthreads();                              // LDS free; reuse for ssum
        float* ssum = (float*)&As[0][0][0];           // [2][128]
        for (int i = 0; i < 4; ++i)
            for (int reg = 0; reg < 4; ++reg) {
                float p = 0.f;
                for (int j = 0; j < 4; ++j) p += acc[i][j][reg] * acc[i][j][reg];
                p += __shfl_xor(p, 1); p += __shfl_xor(p, 2);
                p += __shfl_xor(p, 4); p += __shfl_xor(p, 8);
                if (r == 0) ssum[(w & 1) * 128 + mb + i * 16 + quad * 4 + reg] = p;
            }
        __syncthreads();
        const float* scp = (g < 16) ? q_scale : k_scale;
        const float smul = (g < 16) ? SM_SCALE : 1.0f;
        float scj[4];
        for (int j = 0; j < 4; ++j) scj[j] = scp[nb + j * 16 + r];
        ushort_t* dst = (g < 16) ? (Q  + (size_t)(n * 16 + g) * SEQ * HD)
                                 : (Kb + (size_t)(n * 4 + g - 16) * SEQ * HD);
        for (int i = 0; i < 4; ++i)
            for (int reg = 0; reg < 4; ++reg) {
                int rl = mb + i * 16 + quad * 4 + reg;
                float ss = ssum[rl] + ssum[128 + rl];
                float iv = rsqrtf(ss * (1.0f / 128.0f) + 1e-6f) * smul;
                size_t lrow = lb + rl;
                for (int j = 0; j < 4; ++j) {
                    int d = nb + j * 16 + r;
                    dst[lrow * HD + d] = f2bf(acc[i][j][reg] * iv * scj[j]);
                }
            }
    } else {
        // V: write transposed directly, packing 4 consecutive l per lane (8 B)
        ushort_t* dstT = Vt + (size_t)(n * 4 + g - 20) * HD * SEQ;
        for (int i = 0; i < 4; ++i)
            for (int j = 0; j < 4; ++j) {
                int d = nb + j * 16 + r;
                ushort_t o[4];
                for (int reg = 0; reg < 4; ++reg) o[reg] = f2bf(acc[i][j][reg]);
                *(uint2*)&dstT[(size_t)d * SEQ + lb + mb + i * 16 + quad * 4] = *(uint2*)o;
            }
    }
}

// --------------------------------------------------- flash causal attention
// R5 change: SWAPPED QK^T — sacc = mfma(K, Q) = S^T, so each lane holds 4
// CONSECUTIVE keys at one fixed q-row (A/B per-lane frag layouts for
// mfma_16x16x32 are identical, so operand swap is legal). Softmax mask+exp
// fully in-lane; P store becomes 8x ds_write_b64 packed pairs (was 32x
// ds_write_b16) under XOR swizzle cc^=(r&7)<<1 (bit0 preserved -> b128
// reads stay chunk-pair-aligned; write/read roundtrip paper-verified).
// Row-denominator: in-lane partials + 2 end-of-rep shfl_xor over quads +
// per-reg shfl redistribute. Attn was LDS-pipe-bound (~5000 cyc/CU/step,
// Ps round-trip ~1500 of it) -> predicted ~-20%.
__global__ __launch_bounds__(256, 2) void attn_kernel(const ushort_t* __restrict__ Q,
                                                      const ushort_t* __restrict__ K,
                                                      const ushort_t* __restrict__ Vt,
                                                      ushort_t* __restrict__ Y) {
    const int pid = blockIdx.x, h = blockIdx.y, n = blockIdx.z;
    const int kvh = h >> 2;
    const ushort_t* Qp = Q  + (size_t)(n * N_HEADS + h) * SEQ * HD;
    const ushort_t* Kp = K  + (size_t)(n * N_KV + kvh) * SEQ * HD;
    const ushort_t* Vp = Vt + (size_t)(n * N_KV + kvh) * HD * SEQ;   // [d][l]

    __shared__ ushort_t Ks[2][64][128];   // 32 KB, chunk-swizzled, dbuf
    __shared__ ushort_t Vts[2][128][64];  // 32 KB, chunk-swizzled ([d][key]), dbuf
    __shared__ ushort_t Ps[128][64];      // 16 KB; rows=q, 16x 8B key-chunks, XOR swz

    const int t = threadIdx.x, w = t >> 6, lane = t & 63, quad = lane >> 4, r = lane & 15;

#define ATTN_STAGE(ct, b)                                                           \
    for (int i = 0; i < 4; ++i) {                                                   \
        int ci = (w * 4 + i) * 64 + lane;                                           \
        {   /* K tile 64x128: 16 chunks/row */                                      \
            int row = ci >> 4, c = ci & 15, cg = c ^ (row & 7);                     \
            gload16(&Kp[(size_t)((ct) * 64 + row) * HD + cg * 8],                   \
                    &Ks[b][0][0] + (w * 4 + i) * 512);                              \
        }                                                                           \
        {   /* Vt tile 128x64: 8 chunks/row */                                      \
            int row = ci >> 3, c = ci & 7, cg = c ^ (row & 7);                      \
            gload16(&Vp[(size_t)row * SEQ + (ct) * 64 + cg * 8],                    \
                    &Vts[b][0][0] + (w * 4 + i) * 512);                             \
        }                                                                           \
    }

    for (int rep = 0; rep < 2; ++rep) {
        const int qt = rep ? (15 - pid) : pid;
        const int q0 = qt * 128;

        __syncthreads();   // prev rep's LDS reads done before restaging buf 0
        ATTN_STAGE(0, 0)

        // Q fragments straight from global (A-layout is contiguous 16B/lane)
        bf16x8 aq[2][4];
        for (int s = 0; s < 2; ++s)
            for (int kc = 0; kc < 4; ++kc)
                aq[s][kc] = *(const bf16x8*)&Qp[(size_t)(q0 + w * 32 + s * 16 + r) * HD + kc * 32 + quad * 8];

        f32x4 oacc[2][8] = {};
        float lsum[2] = {};
        const int nct = 2 * qt + 2;
        int buf = 0;

        for (int ct = 0; ct < nct; ++ct) {
            __syncthreads();   // drains DMA into buf; all reads of buf^1 done
            if (ct + 1 < nct) { ATTN_STAGE(ct + 1, buf ^ 1) }

            // skip tiles entirely above the causal boundary for this wave
            if (ct * 64 <= q0 + w * 32 + 31) {
                // S^T strips: mfma(K-as-A, Q-as-B); lane = 4 keys x 1 q-row
                f32x4 sacc[2][4] = {};
                for (int kc = 0; kc < 4; ++kc)
                    for (int jt = 0; jt < 4; ++jt) {
                        bf16x8 bk = *(const bf16x8*)&Ks[buf][jt * 16 + r][((kc * 4 + quad) ^ (r & 7)) * 8];
                        sacc[0][jt] = __builtin_amdgcn_mfma_f32_16x16x32_bf16(bk, aq[0][kc], sacc[0][jt], 0, 0, 0);
                        sacc[1][jt] = __builtin_amdgcn_mfma_f32_16x16x32_bf16(bk, aq[1][kc], sacc[1][jt], 0, 0, 0);
                    }

                // in-lane fixed-max softmax; P truncated bf16, packed b64 stores
                const bool diag = (ct >= 2 * qt);
                for (int s = 0; s < 2; ++s) {
                    const int qg = q0 + w * 32 + s * 16 + r;    // this lane's q-row
                    const int prow = w * 32 + s * 16 + r;
                    float rs = 0.f;
                    for (int jt = 0; jt < 4; ++jt) {
                        uint_t pk[2];
                        for (int pr = 0; pr < 2; ++pr) {
                            float e[2];
                            for (int u = 0; u < 2; ++u) {
                                int reg = pr * 2 + u;
                                int key = ct * 64 + jt * 16 + quad * 4 + reg;
                                float sv = sacc[s][jt][reg];
                                if (diag && key > qg) sv = -1e30f;
                                e[u] = __expf(sv);
                                rs += e[u];
                            }
                            pk[pr] = (__float_as_uint(e[0]) >> 16) |
                                     (__float_as_uint(e[1]) & 0xFFFF0000u);
                        }
                        int cc = (jt * 4 + quad) ^ ((r & 7) << 1);
                        *(uint2*)&Ps[prow][cc * 4] = make_uint2(pk[0], pk[1]);
                    }
                    lsum[s] += rs;
                }

                // PV: O[2x16x128] += P @ V ; pa from new Ps layout; Ps wave-private
                for (int kk = 0; kk < 64; kk += 32) {
                    const int kb = kk >> 5;
                    bf16x8 pa[2];
                    for (int s = 0; s < 2; ++s) {
                        int prow = w * 32 + s * 16 + r;
                        int cc = (kb * 8 + quad * 2) ^ ((r & 7) << 1);
                        pa[s] = *(const bf16x8*)&Ps[prow][cc * 4];
                    }
                    for (int dt = 0; dt < 8; ++dt) {
                        bf16x8 bv = *(const bf16x8*)&Vts[buf][dt * 16 + r][((((kk >> 3) + quad) ^ (r & 7)) & 7) * 8];
                        oacc[0][dt] = __builtin_amdgcn_mfma_f32_16x16x32_bf16(pa[0], bv, oacc[0][dt], 0, 0, 0);
                        oacc[1][dt] = __builtin_amdgcn_mfma_f32_16x16x32_bf16(pa[1], bv, oacc[1][dt], 0, 0, 0);
                    }
                }
            }
            buf ^= 1;
        }

        // epilogue: quad-reduce the in-lane denominators, redistribute, store Y
        for (int s = 0; s < 2; ++s) {
            float ls = lsum[s];
            ls += __shfl_xor(ls, 16);
            ls += __shfl_xor(ls, 32);      // full row-sum for q = q0+w*32+s*16+r
            float inv = 1.0f / ls;
            for (int reg = 0; reg < 4; ++reg) {
                float invl = __shfl(inv, quad * 4 + reg);   // denom for this oacc row
                int lrow = q0 + w * 32 + s * 16 + quad * 4 + reg;
                size_t base = ((size_t)(n * SEQ + lrow)) * D_MODEL + h * HD;
                for (int dt = 0; dt < 8; ++dt)
                    Y[base + dt * 16 + r] = f2bf(oacc[s][dt][reg] * invl);
            }
        }
    }
#undef ATTN_STAGE
}

// ------------------------------------------------------------------ launch
extern "C" void kernel_launch(void* const* d_in, const int* in_sizes, int n_in,
                              void* d_out, int out_size, void* d_ws, size_t ws_size,
                              hipStream_t stream) {
    const float* x       = (const float*)d_in[0];
    const float* Wqkv    = (const float*)d_in[1];
    const float* bqkv    = (const float*)d_in[2];
    const float* q_scale = (const float*)d_in[3];
    const float* k_scale = (const float*)d_in[4];
    const float* Wout    = (const float*)d_in[5];
    const float* bout    = (const float*)d_in[6];
    float* out = (float*)d_out;

    ushort_t* xb  = (ushort_t*)d_ws;                        // 8192*2048 (later: y)
    ushort_t* WT  = xb  + (size_t)MROWS * D_MODEL;          // 3072*2048 (later: WoutT)
    ushort_t* Qb  = WT  + (size_t)NQKV * D_MODEL;           // 4*16*2048*128
    ushort_t* Kb  = Qb  + (size_t)NB * N_HEADS * SEQ * HD;  // 4*4*2048*128
    ushort_t* Vtb = Kb  + (size_t)NB * N_KV * SEQ * HD;     // 4*4*128*2048

    conv_x_kernel<<<MROWS * D_MODEL / 2048, 256, 0, stream>>>(x, xb, MROWS * D_MODEL);
    conv_wt_kernel<<<dim3(NQKV / 32, D_MODEL / 32), dim3(32, 8), 0, stream>>>(Wqkv, WT, D_MODEL, NQKV);
    gemm_qkv_kernel<<<dim3(MROWS / 128, NQKV / 128), 256, 0, stream>>>(xb, WT, bqkv, q_scale, k_scale, Qb, Kb, Vtb);
    conv_wt_kernel<<<dim3(D_MODEL / 32, D_MODEL / 32), dim3(32, 8), 0, stream>>>(Wout, WT, D_MODEL, D_MODEL);
    attn_kernel<<<dim3(8, N_HEADS, NB), 256, 0, stream>>>(Qb, Kb, Vtb, xb);
    gemm_bt_kernel<<<dim3(MROWS / 128, D_MODEL / 128), 256, 0, stream>>>(xb, WT, bout, out, MROWS, D_MODEL, D_MODEL);
}

// Round 6
// 448.460 us; speedup vs baseline: 1.0165x; 1.0065x over previous
//
#include <hip/hip_runtime.h>

typedef unsigned int uint_t;
typedef unsigned short ushort_t;

using f32x4 = __attribute__((ext_vector_type(4))) float;
using bf16x8 = __attribute__((ext_vector_type(8))) short;

#define D_MODEL 2048
#define N_HEADS 16
#define N_KV    4
#define HD      128
#define KV_DIM  (N_KV * HD)          // 512
#define NQKV    (D_MODEL + 2*KV_DIM) // 3072
#define SEQ     2048
#define NB      4
#define MROWS   (NB * SEQ)           // 8192
#define SM_SCALE 0.08838834764831845f  // 1/sqrt(128)

__device__ __forceinline__ ushort_t f2bf(float f) {
    uint_t u = __float_as_uint(f);
    u = (u + 0x7FFFu + ((u >> 16) & 1u)) >> 16;   // RNE
    return (ushort_t)u;
}

// async global->LDS, 16 B/lane, lands at (wave-uniform lds base) + lane*16
__device__ __forceinline__ void gload16(const ushort_t* g, ushort_t* l) {
    __builtin_amdgcn_global_load_lds(
        (const __attribute__((address_space(1))) unsigned int*)g,
        (__attribute__((address_space(3))) unsigned int*)l, 16, 0, 0);
}

// ---------------------------------------------------------------- conv_x
// 8 floats/thread: 32B read + 16B write per lane
__global__ __launch_bounds__(256) void conv_x_kernel(const float* __restrict__ in,
                                                     ushort_t* __restrict__ out, int n) {
    int i = (blockIdx.x * 256 + threadIdx.x) * 8;
    if (i >= n) return;
    float4 v0 = *(const float4*)&in[i];
    float4 v1 = *(const float4*)&in[i + 4];
    ushort_t o[8] = {f2bf(v0.x), f2bf(v0.y), f2bf(v0.z), f2bf(v0.w),
                     f2bf(v1.x), f2bf(v1.y), f2bf(v1.z), f2bf(v1.w)};
    *(uint4*)&out[i] = *(uint4*)o;
}

// ------------------------------------------------------ transpose + cast
// W [K][Nout] fp32 -> WT [Nout][K] bf16
__global__ __launch_bounds__(256) void conv_wt_kernel(const float* __restrict__ W,
                                                      ushort_t* __restrict__ WT,
                                                      int K, int Nout) {
    __shared__ float tile[32][33];
    int n0 = blockIdx.x * 32, k0 = blockIdx.y * 32;
    int tx = threadIdx.x, ty = threadIdx.y;  // (32, 8)
    for (int i = 0; i < 4; ++i)
        tile[ty + 8*i][tx] = W[(size_t)(k0 + ty + 8*i) * Nout + n0 + tx];
    __syncthreads();
    for (int i = 0; i < 4; ++i)
        WT[(size_t)(n0 + ty + 8*i) * K + k0 + tx] = f2bf(tile[tx][ty + 8*i]);
}

// ======================================================================
// 128x128 GEMM core (R0-verified: qkv 127-129 us / ~800 TF, MfmaUtil 34%).
// 4 waves, dbuf LDS, one __syncthreads per 64-K step. FROZEN.
// ======================================================================
#define GEMM_STAGE(A, BT, k0, b)                                                   \
    for (int i = 0; i < 4; ++i) {                                                  \
        int ci = (w * 4 + i) * 64 + lane;                                          \
        int row = ci >> 3, c = ci & 7, cg = c ^ (row & 7);                         \
        gload16(&A [(size_t)(bm + row) * K + (k0) + cg * 8], &As[b][0][0] + (w * 4 + i) * 512); \
        gload16(&BT[(size_t)(bn + row) * K + (k0) + cg * 8], &Bs[b][0][0] + (w * 4 + i) * 512); \
    }

#define GEMM_MAIN_LOOP(A, BT, K)                                                   \
    GEMM_STAGE(A, BT, 0, 0)                                                        \
    {                                                                              \
        int buf = 0;                                                               \
        for (int k0 = 0; k0 < K; k0 += 64) {                                       \
            __syncthreads();            /* drains prefetch into As[buf] */         \
            if (k0 + 64 < K) { GEMM_STAGE(A, BT, k0 + 64, buf ^ 1) }               \
            for (int kk = 0; kk < 64; kk += 32) {                                  \
                bf16x8 af[4], bfr[4];                                              \
                int k4 = kk >> 3;                                                  \
                for (int i = 0; i < 4; ++i)                                        \
                    af[i]  = *(const bf16x8*)&As[buf][mb + i * 16 + r][((k4 + quad) ^ (r & 7)) * 8]; \
                for (int j = 0; j < 4; ++j)                                        \
                    bfr[j] = *(const bf16x8*)&Bs[buf][nb + j * 16 + r][((k4 + quad) ^ (r & 7)) * 8]; \
                for (int i = 0; i < 4; ++i)                                        \
                    for (int j = 0; j < 4; ++j)                                    \
                        acc[i][j] = __builtin_amdgcn_mfma_f32_16x16x32_bf16(af[i], bfr[j], acc[i][j], 0, 0, 0); \
            }                                                                      \
            buf ^= 1;                                                              \
        }                                                                          \
    }

// ---------------------------------------------------- out-projection GEMM
__global__ __launch_bounds__(256) void gemm_bt_kernel(const ushort_t* __restrict__ A,
                                                      const ushort_t* __restrict__ BT,
                                                      const float* __restrict__ bias,
                                                      float* __restrict__ C,
                                                      int M, int N, int K) {
    __shared__ ushort_t As[2][128][64];
    __shared__ ushort_t Bs[2][128][64];
    const int bm = blockIdx.x * 128, bn = blockIdx.y * 128;
    const int t = threadIdx.x;
    const int w = t >> 6, lane = t & 63, quad = lane >> 4, r = lane & 15;
    const int mb = (w >> 1) * 64, nb = (w & 1) * 64;
    f32x4 acc[4][4] = {};
    GEMM_MAIN_LOOP(A, BT, K)
    for (int i = 0; i < 4; ++i)
        for (int j = 0; j < 4; ++j)
            for (int reg = 0; reg < 4; ++reg) {
                int row = bm + mb + i * 16 + quad * 4 + reg;
                int col = bn + nb + j * 16 + r;
                C[(size_t)row * N + col] = acc[i][j][reg] + bias[col];
            }
}

// ------------------------------------- QKV GEMM + fused RMSNorm/rearrange
// N-tile 128 == one head group. g = blockIdx.y: 0..15 -> Q (rmsnorm*q_scale*SM),
// 16..19 -> K (rmsnorm*k_scale), 20..23 -> V transposed directly to Vt [nk][d][l].
__global__ __launch_bounds__(256) void gemm_qkv_kernel(const ushort_t* __restrict__ A,
                                                       const ushort_t* __restrict__ BT,
                                                       const float* __restrict__ bias,
                                                       const float* __restrict__ q_scale,
                                                       const float* __restrict__ k_scale,
                                                       ushort_t* __restrict__ Q,
                                                       ushort_t* __restrict__ Kb,
                                                       ushort_t* __restrict__ Vt) {
    __shared__ ushort_t As[2][128][64];
    __shared__ ushort_t Bs[2][128][64];
    const int K = D_MODEL;
    const int bm = blockIdx.x * 128, bn = blockIdx.y * 128;
    const int t = threadIdx.x;
    const int w = t >> 6, lane = t & 63, quad = lane >> 4, r = lane & 15;
    const int mb = (w >> 1) * 64, nb = (w & 1) * 64;
    f32x4 acc[4][4] = {};
    GEMM_MAIN_LOOP(A, BT, K)

    const int g = blockIdx.y;
    float bj[4];
    for (int j = 0; j < 4; ++j) bj[j] = bias[bn + nb + j * 16 + r];
    for (int i = 0; i < 4; ++i)
        for (int j = 0; j < 4; ++j)
            for (int reg = 0; reg < 4; ++reg) acc[i][j][reg] += bj[j];

    const int n = bm >> 11, lb = bm & 2047;
    if (g < 20) {
        __syncthreads();                              // LDS free; reuse for ssum
        float* ssum = (float*)&As[0][0][0];           // [2][128]
        for (int i = 0; i < 4; ++i)
            for (int reg = 0; reg < 4; ++reg) {
                float p = 0.f;
                for (int j = 0; j < 4; ++j) p += acc[i][j][reg] * acc[i][j][reg];
                p += __shfl_xor(p, 1); p += __shfl_xor(p, 2);
                p += __shfl_xor(p, 4); p += __shfl_xor(p, 8);
                if (r == 0) ssum[(w & 1) * 128 + mb + i * 16 + quad * 4 + reg] = p;
            }
        __syncthreads();
        const float* scp = (g < 16) ? q_scale : k_scale;
        const float smul = (g < 16) ? SM_SCALE : 1.0f;
        float scj[4];
        for (int j = 0; j < 4; ++j) scj[j] = scp[nb + j * 16 + r];
        ushort_t* dst = (g < 16) ? (Q  + (size_t)(n * 16 + g) * SEQ * HD)
                                 : (Kb + (size_t)(n * 4 + g - 16) * SEQ * HD);
        for (int i = 0; i < 4; ++i)
            for (int reg = 0; reg < 4; ++reg) {
                int rl = mb + i * 16 + quad * 4 + reg;
                float ss = ssum[rl] + ssum[128 + rl];
                float iv = rsqrtf(ss * (1.0f / 128.0f) + 1e-6f) * smul;
                size_t lrow = lb + rl;
                for (int j = 0; j < 4; ++j) {
                    int d = nb + j * 16 + r;
                    dst[lrow * HD + d] = f2bf(acc[i][j][reg] * iv * scj[j]);
                }
            }
    } else {
        // V: write transposed directly, packing 4 consecutive l per lane (8 B)
        ushort_t* dstT = Vt + (size_t)(n * 4 + g - 20) * HD * SEQ;
        for (int i = 0; i < 4; ++i)
            for (int j = 0; j < 4; ++j) {
                int d = nb + j * 16 + r;
                ushort_t o[4];
                for (int reg = 0; reg < 4; ++reg) o[reg] = f2bf(acc[i][j][reg]);
                *(uint2*)&dstT[(size_t)d * SEQ + lb + mb + i * 16 + quad * 4] = *(uint2*)o;
            }
    }
}

// --------------------------------------------------- flash causal attention
// R6: QBLK=256 / 8 waves / 1 block per CU (grid 4x16x4 = 256). Each staged
// 64-key KV tile now serves 256 q-rows instead of 128: per-CU step count
// drops 68 -> 36, halving staging DMA bytes, DMA issues and barrier-drain
// events, while compute-side LDS reads / MFMA are unchanged. Wave-level
// code is IDENTICAL to the verified R5 kernel (swapped-QK in-lane softmax,
// packed b64 Ps stores); only geometry scales: w in 0..7, q0 = qt*256,
// nct = 4qt+4, diag at ct>=4qt, Ps[256][64]. LDS 32+32+32 = 96 KB.
__global__ __launch_bounds__(512, 1) void attn_kernel(const ushort_t* __restrict__ Q,
                                                      const ushort_t* __restrict__ K,
                                                      const ushort_t* __restrict__ Vt,
                                                      ushort_t* __restrict__ Y) {
    const int pid = blockIdx.x, h = blockIdx.y, n = blockIdx.z;
    const int kvh = h >> 2;
    const ushort_t* Qp = Q  + (size_t)(n * N_HEADS + h) * SEQ * HD;
    const ushort_t* Kp = K  + (size_t)(n * N_KV + kvh) * SEQ * HD;
    const ushort_t* Vp = Vt + (size_t)(n * N_KV + kvh) * HD * SEQ;   // [d][l]

    __shared__ ushort_t Ks[2][64][128];   // 32 KB, chunk-swizzled, dbuf
    __shared__ ushort_t Vts[2][128][64];  // 32 KB, chunk-swizzled ([d][key]), dbuf
    __shared__ ushort_t Ps[256][64];      // 32 KB; rows=q, 16x 8B key-chunks, XOR swz

    const int t = threadIdx.x, w = t >> 6, lane = t & 63, quad = lane >> 4, r = lane & 15;

// 8 waves x 2 chunks each cover the 16KB K tile and 16KB V tile per step
#define ATTN_STAGE(ct, b)                                                           \
    for (int i = 0; i < 2; ++i) {                                                   \
        int ci = (w * 2 + i) * 64 + lane;                                           \
        {   /* K tile 64x128: 16 chunks/row */                                      \
            int row = ci >> 4, c = ci & 15, cg = c ^ (row & 7);                     \
            gload16(&Kp[(size_t)((ct) * 64 + row) * HD + cg * 8],                   \
                    &Ks[b][0][0] + (w * 2 + i) * 512);                              \
        }                                                                           \
        {   /* Vt tile 128x64: 8 chunks/row */                                      \
            int row = ci >> 3, c = ci & 7, cg = c ^ (row & 7);                      \
            gload16(&Vp[(size_t)row * SEQ + (ct) * 64 + cg * 8],                    \
                    &Vts[b][0][0] + (w * 2 + i) * 512);                             \
        }                                                                           \
    }

    for (int rep = 0; rep < 2; ++rep) {
        const int qt = rep ? (7 - pid) : pid;
        const int q0 = qt * 256;

        __syncthreads();   // prev rep's LDS reads done before restaging buf 0
        ATTN_STAGE(0, 0)

        // Q fragments straight from global (A-layout is contiguous 16B/lane)
        bf16x8 aq[2][4];
        for (int s = 0; s < 2; ++s)
            for (int kc = 0; kc < 4; ++kc)
                aq[s][kc] = *(const bf16x8*)&Qp[(size_t)(q0 + w * 32 + s * 16 + r) * HD + kc * 32 + quad * 8];

        f32x4 oacc[2][8] = {};
        float lsum[2] = {};
        const int nct = 4 * qt + 4;
        int buf = 0;

        for (int ct = 0; ct < nct; ++ct) {
            __syncthreads();   // drains DMA into buf; all reads of buf^1 done
            if (ct + 1 < nct) { ATTN_STAGE(ct + 1, buf ^ 1) }

            // skip tiles entirely above the causal boundary for this wave
            if (ct * 64 <= q0 + w * 32 + 31) {
                // S^T strips: mfma(K-as-A, Q-as-B); lane = 4 keys x 1 q-row
                f32x4 sacc[2][4] = {};
                for (int kc = 0; kc < 4; ++kc)
                    for (int jt = 0; jt < 4; ++jt) {
                        bf16x8 bk = *(const bf16x8*)&Ks[buf][jt * 16 + r][((kc * 4 + quad) ^ (r & 7)) * 8];
                        sacc[0][jt] = __builtin_amdgcn_mfma_f32_16x16x32_bf16(bk, aq[0][kc], sacc[0][jt], 0, 0, 0);
                        sacc[1][jt] = __builtin_amdgcn_mfma_f32_16x16x32_bf16(bk, aq[1][kc], sacc[1][jt], 0, 0, 0);
                    }

                // in-lane fixed-max softmax; P truncated bf16, packed b64 stores
                const bool diag = (ct >= 4 * qt);
                for (int s = 0; s < 2; ++s) {
                    const int qg = q0 + w * 32 + s * 16 + r;    // this lane's q-row
                    const int prow = w * 32 + s * 16 + r;
                    float rs = 0.f;
                    for (int jt = 0; jt < 4; ++jt) {
                        uint_t pk[2];
                        for (int pr = 0; pr < 2; ++pr) {
                            float e[2];
                            for (int u = 0; u < 2; ++u) {
                                int reg = pr * 2 + u;
                                int key = ct * 64 + jt * 16 + quad * 4 + reg;
                                float sv = sacc[s][jt][reg];
                                if (diag && key > qg) sv = -1e30f;
                                e[u] = __expf(sv);
                                rs += e[u];
                            }
                            pk[pr] = (__float_as_uint(e[0]) >> 16) |
                                     (__float_as_uint(e[1]) & 0xFFFF0000u);
                        }
                        int cc = (jt * 4 + quad) ^ ((r & 7) << 1);
                        *(uint2*)&Ps[prow][cc * 4] = make_uint2(pk[0], pk[1]);
                    }
                    lsum[s] += rs;
                }

                // PV: O[2x16x128] += P @ V ; pa from Ps layout; Ps wave-private
                for (int kk = 0; kk < 64; kk += 32) {
                    const int kb = kk >> 5;
                    bf16x8 pa[2];
                    for (int s = 0; s < 2; ++s) {
                        int prow = w * 32 + s * 16 + r;
                        int cc = (kb * 8 + quad * 2) ^ ((r & 7) << 1);
                        pa[s] = *(const bf16x8*)&Ps[prow][cc * 4];
                    }
                    for (int dt = 0; dt < 8; ++dt) {
                        bf16x8 bv = *(const bf16x8*)&Vts[buf][dt * 16 + r][((((kk >> 3) + quad) ^ (r & 7)) & 7) * 8];
                        oacc[0][dt] = __builtin_amdgcn_mfma_f32_16x16x32_bf16(pa[0], bv, oacc[0][dt], 0, 0, 0);
                        oacc[1][dt] = __builtin_amdgcn_mfma_f32_16x16x32_bf16(pa[1], bv, oacc[1][dt], 0, 0, 0);
                    }
                }
            }
            buf ^= 1;
        }

        // epilogue: quad-reduce the in-lane denominators, redistribute, store Y
        for (int s = 0; s < 2; ++s) {
            float ls = lsum[s];
            ls += __shfl_xor(ls, 16);
            ls += __shfl_xor(ls, 32);      // full row-sum for q = q0+w*32+s*16+r
            float inv = 1.0f / ls;
            for (int reg = 0; reg < 4; ++reg) {
                float invl = __shfl(inv, quad * 4 + reg);   // denom for this oacc row
                int lrow = q0 + w * 32 + s * 16 + quad * 4 + reg;
                size_t base = ((size_t)(n * SEQ + lrow)) * D_MODEL + h * HD;
                for (int dt = 0; dt < 8; ++dt)
                    Y[base + dt * 16 + r] = f2bf(oacc[s][dt][reg] * invl);
            }
        }
    }
#undef ATTN_STAGE
}

// ------------------------------------------------------------------ launch
extern "C" void kernel_launch(void* const* d_in, const int* in_sizes, int n_in,
                              void* d_out, int out_size, void* d_ws, size_t ws_size,
                              hipStream_t stream) {
    const float* x       = (const float*)d_in[0];
    const float* Wqkv    = (const float*)d_in[1];
    const float* bqkv    = (const float*)d_in[2];
    const float* q_scale = (const float*)d_in[3];
    const float* k_scale = (const float*)d_in[4];
    const float* Wout    = (const float*)d_in[5];
    const float* bout    = (const float*)d_in[6];
    float* out = (float*)d_out;

    ushort_t* xb  = (ushort_t*)d_ws;                        // 8192*2048 (later: y)
    ushort_t* WT  = xb  + (size_t)MROWS * D_MODEL;          // 3072*2048 (later: WoutT)
    ushort_t* Qb  = WT  + (size_t)NQKV * D_MODEL;           // 4*16*2048*128
    ushort_t* Kb  = Qb  + (size_t)NB * N_HEADS * SEQ * HD;  // 4*4*2048*128
    ushort_t* Vtb = Kb  + (size_t)NB * N_KV * SEQ * HD;     // 4*4*128*2048

    conv_x_kernel<<<MROWS * D_MODEL / 2048, 256, 0, stream>>>(x, xb, MROWS * D_MODEL);
    conv_wt_kernel<<<dim3(NQKV / 32, D_MODEL / 32), dim3(32, 8), 0, stream>>>(Wqkv, WT, D_MODEL, NQKV);
    gemm_qkv_kernel<<<dim3(MROWS / 128, NQKV / 128), 256, 0, stream>>>(xb, WT, bqkv, q_scale, k_scale, Qb, Kb, Vtb);
    conv_wt_kernel<<<dim3(D_MODEL / 32, D_MODEL / 32), dim3(32, 8), 0, stream>>>(Wout, WT, D_MODEL, D_MODEL);
    attn_kernel<<<dim3(4, N_HEADS, NB), 512, 0, stream>>>(Qb, Kb, Vtb, xb);
    gemm_bt_kernel<<<dim3(MROWS / 128, D_MODEL / 128), 256, 0, stream>>>(xb, WT, bout, out, MROWS, D_MODEL, D_MODEL);
}